// Round 1
// baseline (555.102 us; speedup 1.0000x reference)
//
#include <hip/hip_runtime.h>
#include <math.h>

#define KCOMP 32
#define DDIM 64
#define NPTS 65536
#define LOG_2PI 1.8378770664093453f

// ---------------------------------------------------------------------------
// Prep kernel: per-component Cholesky, triangular inverse, b = M*mu, const_k.
// grid = KCOMP blocks, 64 threads each.
// ---------------------------------------------------------------------------
__global__ __launch_bounds__(64) void gmm_prep(const float* __restrict__ loc,
                                               const float* __restrict__ cov,
                                               const float* __restrict__ pi,
                                               float* __restrict__ Mout,   // [K][D][D]
                                               float* __restrict__ bout,   // [K][D]
                                               float* __restrict__ cstout) // [K]
{
    const int k = blockIdx.x;
    const int t = threadIdx.x;

    __shared__ float L[DDIM][DDIM + 1];
    __shared__ float Msh[DDIM][DDIM + 1];
    __shared__ float s_hld;

    // load cov_k
    for (int i = 0; i < DDIM; ++i)
        L[i][t] = cov[(size_t)k * DDIM * DDIM + i * DDIM + t];
    __syncthreads();

    // right-looking Cholesky (lower)
    for (int j = 0; j < DDIM; ++j) {
        if (t == j) L[j][j] = sqrtf(L[j][j]);
        __syncthreads();
        float inv = 1.0f / L[j][j];
        if (t > j) L[t][j] *= inv;
        __syncthreads();
        if (t > j) {
            float ltj = L[t][j];
            for (int c = j + 1; c <= t; ++c) L[t][c] -= ltj * L[c][j];
        }
        __syncthreads();
    }

    if (t == 0) {
        float hld = 0.f;
        for (int j = 0; j < DDIM; ++j) hld += logf(L[j][j]);
        s_hld = hld;
    }

    // M = L^{-1}: thread t computes column t (forward substitution)
    for (int i = 0; i < t; ++i) Msh[i][t] = 0.f;   // upper strictly zero
    Msh[t][t] = 1.0f / L[t][t];
    for (int i = t + 1; i < DDIM; ++i) {
        float s = 0.f;
        for (int c = t; c < i; ++c) s += L[i][c] * Msh[c][t];
        Msh[i][t] = -s / L[i][i];
    }
    __syncthreads();

    // b_t = sum_j M[t][j] * mu[j]  (j <= t, upper is zero)
    float bt = 0.f;
    for (int j = 0; j <= t; ++j) bt += Msh[t][j] * loc[k * DDIM + j];
    bout[k * DDIM + t] = bt;

    // store M row-major, coalesced over t
    for (int i = 0; i < DDIM; ++i)
        Mout[(size_t)k * DDIM * DDIM + i * DDIM + t] = Msh[i][t];

    if (t == 0) {
        // log_softmax(pi)[k] = pi[k] - logsumexp(pi)
        float mx = pi[0];
        for (int i = 1; i < KCOMP; ++i) mx = fmaxf(mx, pi[i]);
        float s = 0.f;
        for (int i = 0; i < KCOMP; ++i) s += __expf(pi[i] - mx);
        float lse = mx + logf(s);
        cstout[k] = (pi[k] - lse) - s_hld - 0.5f * (float)DDIM * LOG_2PI;
    }
}

// ---------------------------------------------------------------------------
// Main kernel: one point per thread; loop components, M_k staged in LDS.
// grid = 256 blocks x 256 threads = 65536 threads.
// ---------------------------------------------------------------------------
__global__ __launch_bounds__(256) void gmm_main(const float* __restrict__ X,
                                                const float* __restrict__ M,
                                                const float* __restrict__ b,
                                                const float* __restrict__ cst,
                                                float* __restrict__ out)
{
    const int n = blockIdx.x * 256 + threadIdx.x;

    float x[DDIM];
    {
        const float4* X4 = reinterpret_cast<const float4*>(X + (size_t)n * DDIM);
        #pragma unroll
        for (int r = 0; r < DDIM / 4; ++r) {
            float4 v = X4[r];
            x[r * 4 + 0] = v.x; x[r * 4 + 1] = v.y;
            x[r * 4 + 2] = v.z; x[r * 4 + 3] = v.w;
        }
    }

    __shared__ float Ms[DDIM * DDIM];   // 16 KB

    float mx = -INFINITY, sm = 0.f;

    for (int k = 0; k < KCOMP; ++k) {
        __syncthreads();
        // stage M_k into LDS, coalesced float4
        #pragma unroll
        for (int r = 0; r < 4; ++r) {
            int idx = r * 1024 + threadIdx.x * 4;
            *reinterpret_cast<float4*>(&Ms[idx]) =
                *reinterpret_cast<const float4*>(&M[(size_t)k * DDIM * DDIM + idx]);
        }
        __syncthreads();

        float maha = 0.f;
        #pragma unroll
        for (int i = 0; i < DDIM; i += 4) {
            float z0 = -b[k * DDIM + i + 0];
            float z1 = -b[k * DDIM + i + 1];
            float z2 = -b[k * DDIM + i + 2];
            float z3 = -b[k * DDIM + i + 3];
            // lower-triangular: rows i..i+3 only need j <= i+3 (upper M is 0)
            #pragma unroll
            for (int j = 0; j <= i + 3; j += 4) {
                float4 m0 = *reinterpret_cast<const float4*>(&Ms[(i + 0) * DDIM + j]);
                float4 m1 = *reinterpret_cast<const float4*>(&Ms[(i + 1) * DDIM + j]);
                float4 m2 = *reinterpret_cast<const float4*>(&Ms[(i + 2) * DDIM + j]);
                float4 m3 = *reinterpret_cast<const float4*>(&Ms[(i + 3) * DDIM + j]);
                z0 += m0.x * x[j] + m0.y * x[j + 1] + m0.z * x[j + 2] + m0.w * x[j + 3];
                z1 += m1.x * x[j] + m1.y * x[j + 1] + m1.z * x[j + 2] + m1.w * x[j + 3];
                z2 += m2.x * x[j] + m2.y * x[j + 1] + m2.z * x[j + 2] + m2.w * x[j + 3];
                z3 += m3.x * x[j] + m3.y * x[j + 1] + m3.z * x[j + 2] + m3.w * x[j + 3];
            }
            maha += z0 * z0 + z1 * z1 + z2 * z2 + z3 * z3;
        }

        float lp = cst[k] - 0.5f * maha;
        float nm = fmaxf(mx, lp);
        sm = sm * __expf(mx - nm) + __expf(lp - nm);
        mx = nm;
    }

    out[n] = mx + logf(sm);
}

// ---------------------------------------------------------------------------
extern "C" void kernel_launch(void* const* d_in, const int* in_sizes, int n_in,
                              void* d_out, int out_size, void* d_ws, size_t ws_size,
                              hipStream_t stream) {
    const float* X   = (const float*)d_in[0];
    const float* loc = (const float*)d_in[1];
    const float* cov = (const float*)d_in[2];
    const float* pi  = (const float*)d_in[3];
    float* out = (float*)d_out;

    char* ws = (char*)d_ws;
    float* Mout = (float*)ws;                                  // 512 KB
    float* bout = (float*)(ws + (size_t)KCOMP * DDIM * DDIM * 4);  // 8 KB
    float* csto = (float*)(ws + (size_t)KCOMP * DDIM * DDIM * 4 + KCOMP * DDIM * 4);

    gmm_prep<<<KCOMP, 64, 0, stream>>>(loc, cov, pi, Mout, bout, csto);
    gmm_main<<<NPTS / 256, 256, 0, stream>>>(X, Mout, bout, csto, out);
}

// Round 2
// 155.243 us; speedup vs baseline: 3.5757x; 3.5757x over previous
//
#include <hip/hip_runtime.h>
#include <math.h>

#define KCOMP 32
#define DDIM 64
#define LOG_2PI 1.8378770664093453f

#define WROW 128                      // f16 per swizzled W row (16 chunks x 8)
#define WBYTES (DDIM * WROW * 2)      // 16384 B per component

typedef _Float16 half8 __attribute__((ext_vector_type(8)));
typedef float floatx16 __attribute__((ext_vector_type(16)));

__device__ inline void gload_lds16(const void* g, void* l) {
    __builtin_amdgcn_global_load_lds(
        (const __attribute__((address_space(1))) void*)g,
        (__attribute__((address_space(3))) void*)l, 16, 0, 0);
}

// ---------------------------------------------------------------------------
// Prep: per-component Cholesky, L^{-1}, emit swizzled f16 W~ (M | -b_hi,-b_lo)
// and cst_k. grid = KCOMP blocks x 64 threads.
// ---------------------------------------------------------------------------
__global__ __launch_bounds__(64) void gmm_prep(const float* __restrict__ loc,
                                               const float* __restrict__ cov,
                                               const float* __restrict__ pi,
                                               _Float16* __restrict__ wt,
                                               float* __restrict__ cstout)
{
    const int k = blockIdx.x;
    const int t = threadIdx.x;

    __shared__ float L[DDIM][DDIM + 1];
    __shared__ float Msh[DDIM][DDIM + 1];
    __shared__ float s_hld;

    for (int i = 0; i < DDIM; ++i)
        L[i][t] = cov[(size_t)k * DDIM * DDIM + i * DDIM + t];
    __syncthreads();

    // right-looking Cholesky (lower)
    for (int j = 0; j < DDIM; ++j) {
        if (t == j) L[j][j] = sqrtf(L[j][j]);
        __syncthreads();
        float inv = 1.0f / L[j][j];
        if (t > j) L[t][j] *= inv;
        __syncthreads();
        if (t > j) {
            float ltj = L[t][j];
            for (int c = j + 1; c <= t; ++c) L[t][c] -= ltj * L[c][j];
        }
        __syncthreads();
    }

    if (t == 0) {
        float hld = 0.f;
        for (int j = 0; j < DDIM; ++j) hld += logf(L[j][j]);
        s_hld = hld;
    }

    // M = L^{-1}: thread t computes column t (forward substitution)
    for (int i = 0; i < t; ++i) Msh[i][t] = 0.f;
    Msh[t][t] = 1.0f / L[t][t];
    for (int i = t + 1; i < DDIM; ++i) {
        float s = 0.f;
        for (int c = t; c < i; ++c) s += L[i][c] * Msh[c][t];
        Msh[i][t] = -s / L[i][i];
    }
    __syncthreads();

    // b_t = sum_{j<=t} M[t][j] * mu[j]
    float bt = 0.f;
    for (int j = 0; j <= t; ++j) bt += Msh[t][j] * loc[k * DDIM + j];

    // ---- emit swizzled f16 row t of W~ [i=t][q] with chunk XOR swizzle ----
    _Float16* wrow = wt + (size_t)k * DDIM * WROW + (size_t)t * WROW;
    const int g = (t >> 2) & 7;

    #pragma unroll
    for (int c = 0; c < 8; ++c) {          // data chunks: M row
        half8 v;
        #pragma unroll
        for (int e = 0; e < 8; ++e) v[e] = (_Float16)Msh[t][c * 8 + e];
        *(half8*)(wrow + (size_t)(c ^ g) * 8) = v;
    }
    {   // chunk 8: -b split hi/lo (pairs with x~=1,1)
        float nb = -bt;
        _Float16 h0 = (_Float16)nb;
        _Float16 h1 = (_Float16)(nb - (float)h0);
        half8 v;
        #pragma unroll
        for (int e = 0; e < 8; ++e) v[e] = (_Float16)0.f;
        v[0] = h0; v[1] = h1;
        *(half8*)(wrow + (size_t)(8 ^ g) * 8) = v;
    }
    #pragma unroll
    for (int c = 9; c < 16; ++c) {         // zero padding chunks
        half8 v;
        #pragma unroll
        for (int e = 0; e < 8; ++e) v[e] = (_Float16)0.f;
        *(half8*)(wrow + (size_t)(c ^ g) * 8) = v;
    }

    if (t == 0) {
        float mxp = pi[0];
        for (int i = 1; i < KCOMP; ++i) mxp = fmaxf(mxp, pi[i]);
        float s = 0.f;
        for (int i = 0; i < KCOMP; ++i) s += __expf(pi[i] - mxp);
        float lse = mxp + logf(s);
        cstout[k] = (pi[k] - lse) - s_hld - 0.5f * (float)DDIM * LOG_2PI;
    }
}

// ---------------------------------------------------------------------------
// Main: MFMA z = W~ x~ per component; C rows = out-dim i, cols = points.
// 128 threads (2 waves), 64 points per wave. W~ double-buffered in LDS via
// global_load_lds; x~ B-fragments resident in registers for all 32 comps.
// ---------------------------------------------------------------------------
__global__ __launch_bounds__(128) void gmm_main(const float* __restrict__ X,
                                                const _Float16* __restrict__ wt,
                                                const float* __restrict__ cst,
                                                float* __restrict__ out)
{
    __shared__ char wbuf[2][WBYTES];      // 32 KB

    const int tid  = threadIdx.x;
    const int wave = tid >> 6;
    const int lane = tid & 63;
    const int col  = lane & 31;
    const int h    = lane >> 5;
    const int wavebase = blockIdx.x * 128 + wave * 64;

    // issue stage of component 0 into buf 0 (8 KB per wave)
    {
        const char* gsrc = (const char*)wt;
        #pragma unroll
        for (int j = 0; j < 8; ++j) {
            int off = wave * 8192 + j * 1024;
            gload_lds16(gsrc + off + lane * 16, &wbuf[0][off]);
        }
    }

    // build B fragments (x~), overlapping the stage
    half8 bf[2][5];
    #pragma unroll
    for (int pt = 0; pt < 2; ++pt) {
        const float* xr = X + (size_t)(wavebase + pt * 32 + col) * DDIM;
        #pragma unroll
        for (int s = 0; s < 4; ++s) {
            int c = s * 2 + h;
            float4 lo = *(const float4*)(xr + c * 8);
            float4 hi = *(const float4*)(xr + c * 8 + 4);
            half8 v;
            v[0] = (_Float16)lo.x; v[1] = (_Float16)lo.y;
            v[2] = (_Float16)lo.z; v[3] = (_Float16)lo.w;
            v[4] = (_Float16)hi.x; v[5] = (_Float16)hi.y;
            v[6] = (_Float16)hi.z; v[7] = (_Float16)hi.w;
            bf[pt][s] = v;
        }
        half8 v;
        #pragma unroll
        for (int e = 0; e < 8; ++e) v[e] = (_Float16)0.f;
        if (h == 0) { v[0] = (_Float16)1.f; v[1] = (_Float16)1.f; }
        bf[pt][4] = v;   // augmented slice: pairs with (-b_hi, -b_lo)
    }

    float mx0 = -INFINITY, sm0 = 0.f;
    float mx1 = -INFINITY, sm1 = 0.f;

    __syncthreads();   // emits vmcnt(0) drain: stage 0 complete

    const int g0 = col >> 2;   // swizzle key, same for both row-tiles
    int cur = 0;

    for (int k = 0; k < KCOMP; ++k) {
        // prefetch next component into the other buffer
        if (k + 1 < KCOMP) {
            const char* gsrc = (const char*)wt + (size_t)(k + 1) * WBYTES;
            #pragma unroll
            for (int j = 0; j < 8; ++j) {
                int off = wave * 8192 + j * 1024;
                gload_lds16(gsrc + off + lane * 16, &wbuf[cur ^ 1][off]);
            }
        }

        floatx16 a00 = {0.f}, a01 = {0.f}, a10 = {0.f}, a11 = {0.f};
        const char* wb = wbuf[cur];

        #pragma unroll
        for (int s = 0; s < 5; ++s) {
            int c = 2 * s + h;
            int p = c ^ g0;
            half8 A0 = *(const half8*)(wb + (size_t)col * 256 + p * 16);
            half8 A1 = *(const half8*)(wb + (size_t)(col + 32) * 256 + p * 16);
            a00 = __builtin_amdgcn_mfma_f32_32x32x16_f16(A0, bf[0][s], a00, 0, 0, 0);
            a01 = __builtin_amdgcn_mfma_f32_32x32x16_f16(A0, bf[1][s], a01, 0, 0, 0);
            a10 = __builtin_amdgcn_mfma_f32_32x32x16_f16(A1, bf[0][s], a10, 0, 0, 0);
            a11 = __builtin_amdgcn_mfma_f32_32x32x16_f16(A1, bf[1][s], a11, 0, 0, 0);
        }

        // maha = sum_i z_i^2 : per-lane partial over its 32 rows, + pair swap
        float s0 = 0.f, s1 = 0.f;
        #pragma unroll
        for (int r = 0; r < 16; ++r) {
            s0 += a00[r] * a00[r] + a10[r] * a10[r];
            s1 += a01[r] * a01[r] + a11[r] * a11[r];
        }
        s0 += __shfl_xor(s0, 32);
        s1 += __shfl_xor(s1, 32);

        float ck  = cst[k];
        float lp0 = ck - 0.5f * s0;
        float lp1 = ck - 0.5f * s1;
        float nm0 = fmaxf(mx0, lp0);
        sm0 = sm0 * __expf(mx0 - nm0) + __expf(lp0 - nm0); mx0 = nm0;
        float nm1 = fmaxf(mx1, lp1);
        sm1 = sm1 * __expf(mx1 - nm1) + __expf(lp1 - nm1); mx1 = nm1;

        __syncthreads();   // drains vmcnt (prefetch done) + protects buffers
        cur ^= 1;
    }

    if (h == 0) {
        out[wavebase + col]      = mx0 + logf(sm0);
        out[wavebase + 32 + col] = mx1 + logf(sm1);
    }
}

// ---------------------------------------------------------------------------
extern "C" void kernel_launch(void* const* d_in, const int* in_sizes, int n_in,
                              void* d_out, int out_size, void* d_ws, size_t ws_size,
                              hipStream_t stream) {
    const float* X   = (const float*)d_in[0];
    const float* loc = (const float*)d_in[1];
    const float* cov = (const float*)d_in[2];
    const float* pi  = (const float*)d_in[3];
    float* out = (float*)d_out;

    char* ws = (char*)d_ws;
    _Float16* wt = (_Float16*)ws;                                   // 512 KB
    float* cstp  = (float*)(ws + (size_t)KCOMP * DDIM * WROW * 2);  // 128 B

    const int n = in_sizes[0] / DDIM;   // 65536

    gmm_prep<<<KCOMP, 64, 0, stream>>>(loc, cov, pi, wt, cstp);
    gmm_main<<<n / 128, 128, 0, stream>>>(X, wt, cstp, out);
}

// Round 3
// 131.515 us; speedup vs baseline: 4.2208x; 1.1804x over previous
//
#include <hip/hip_runtime.h>
#include <math.h>

#define KCOMP 32
#define DDIM 64
#define LOG_2PI 1.8378770664093453f

#define WROW 128                      // f16 per swizzled W row (16 chunks x 8)
#define WBYTES (DDIM * WROW * 2)      // 16384 B per component

typedef _Float16 half8 __attribute__((ext_vector_type(8)));
typedef float floatx16 __attribute__((ext_vector_type(16)));

__device__ inline void gload_lds16(const void* g, void* l) {
    __builtin_amdgcn_global_load_lds(
        (const __attribute__((address_space(1))) void*)g,
        (__attribute__((address_space(3))) void*)l, 16, 0, 0);
}

// ---------------------------------------------------------------------------
// Prep: per-component left-looking Cholesky + row-sequential triangular
// inverse, all wave-parallel with uniform loop bounds (no divergence).
// Emits swizzled f16 W~ = (M | -b_hi,-b_lo | 0-pad) and cst_k.
// grid = KCOMP blocks x 64 threads (1 wave).
// ---------------------------------------------------------------------------
__global__ __launch_bounds__(64) void gmm_prep(const float* __restrict__ loc,
                                               const float* __restrict__ cov,
                                               const float* __restrict__ pi,
                                               _Float16* __restrict__ wt,
                                               float* __restrict__ cstout)
{
    const int k = blockIdx.x;
    const int t = threadIdx.x;

    __shared__ float S[DDIM][DDIM + 1];
    __shared__ float L[DDIM][DDIM + 1];
    __shared__ float M[DDIM][DDIM + 1];
    __shared__ float mu_s[DDIM];

    // load Sigma (row i, thread t = col), zero-init L, load mu
    for (int i = 0; i < DDIM; ++i) {
        S[i][t] = cov[(size_t)k * DDIM * DDIM + i * DDIM + t];
        L[i][t] = 0.f;
    }
    L[DDIM - 1][DDIM] = 0.f;  // unused pad slot (keep defined)
    mu_s[t] = loc[k * DDIM + t];
    __syncthreads();

    // ---- left-looking Cholesky: step j computes column j ----
    float hld = 0.f;   // uniform across lanes: 0.5 * sum log d_j
    for (int j = 0; j < DDIM; ++j) {
        float s = 0.f, s2 = 0.f;
        #pragma unroll 4
        for (int c = 0; c < j; ++c) {
            if (c & 1) s2 += L[t][c] * L[j][c];
            else       s  += L[t][c] * L[j][c];
        }
        float v = S[t][j] - (s + s2);
        float dj = __shfl(v, j);               // diagonal d_j (pre-sqrt)
        float r = rsqrtf(dj);
        r = r * (1.5f - 0.5f * dj * r * r);    // one Newton step
        float lt = v * r;
        if (t >= j) L[t][j] = lt;
        hld += 0.5f * logf(dj);
        __syncthreads();
    }

    // ---- M = L^{-1}, row-sequential: step i computes row i, thread = col ----
    // upper rows of M hold zeros, so no predicate needed in the dot.
    for (int i = 0; i < DDIM; ++i) {
        float s = 0.f, s2 = 0.f;
        #pragma unroll 4
        for (int c = 0; c < i; ++c) {
            if (c & 1) s2 += L[i][c] * M[c][t];
            else       s  += L[i][c] * M[c][t];
        }
        float dinv = 1.0f / L[i][i];           // uniform
        float mi = (t < i) ? (-(s + s2) * dinv) : ((t == i) ? dinv : 0.f);
        M[i][t] = mi;
        __syncthreads();
    }

    // ---- b_t = sum_{j<=t} M[t][j] * mu[j] ----
    float bt = 0.f;
    #pragma unroll 4
    for (int j = 0; j < DDIM; ++j) bt += M[t][j] * mu_s[j];  // upper is 0

    // ---- emit swizzled f16 row t of W~ ----
    _Float16* wrow = wt + (size_t)k * DDIM * WROW + (size_t)t * WROW;
    const int g = (t >> 2) & 7;

    #pragma unroll
    for (int c = 0; c < 8; ++c) {          // data chunks: M row
        half8 v;
        #pragma unroll
        for (int e = 0; e < 8; ++e) v[e] = (_Float16)M[t][c * 8 + e];
        *(half8*)(wrow + (size_t)(c ^ g) * 8) = v;
    }
    {   // chunk 8: -b split hi/lo (pairs with x~=1,1)
        float nb = -bt;
        _Float16 h0 = (_Float16)nb;
        _Float16 h1 = (_Float16)(nb - (float)h0);
        half8 v;
        #pragma unroll
        for (int e = 0; e < 8; ++e) v[e] = (_Float16)0.f;
        v[0] = h0; v[1] = h1;
        *(half8*)(wrow + (size_t)(8 ^ g) * 8) = v;
    }
    #pragma unroll
    for (int c = 9; c < 16; ++c) {         // zero padding chunks
        half8 v;
        #pragma unroll
        for (int e = 0; e < 8; ++e) v[e] = (_Float16)0.f;
        *(half8*)(wrow + (size_t)(c ^ g) * 8) = v;
    }

    if (t == 0) {
        float mxp = pi[0];
        for (int i = 1; i < KCOMP; ++i) mxp = fmaxf(mxp, pi[i]);
        float s = 0.f;
        for (int i = 0; i < KCOMP; ++i) s += __expf(pi[i] - mxp);
        float lse = mxp + logf(s);
        cstout[k] = (pi[k] - lse) - hld - 0.5f * (float)DDIM * LOG_2PI;
    }
}

// ---------------------------------------------------------------------------
// Main: MFMA z = W~ x~ per component; C rows = out-dim i, cols = points.
// 128 threads (2 waves), 64 points per wave. W~ double-buffered in LDS via
// global_load_lds; x~ B-fragments resident in registers for all 32 comps.
// ---------------------------------------------------------------------------
__global__ __launch_bounds__(128) void gmm_main(const float* __restrict__ X,
                                                const _Float16* __restrict__ wt,
                                                const float* __restrict__ cst,
                                                float* __restrict__ out)
{
    __shared__ char wbuf[2][WBYTES];      // 32 KB

    const int tid  = threadIdx.x;
    const int wave = tid >> 6;
    const int lane = tid & 63;
    const int col  = lane & 31;
    const int h    = lane >> 5;
    const int wavebase = blockIdx.x * 128 + wave * 64;

    // issue stage of component 0 into buf 0 (8 KB per wave)
    {
        const char* gsrc = (const char*)wt;
        #pragma unroll
        for (int j = 0; j < 8; ++j) {
            int off = wave * 8192 + j * 1024;
            gload_lds16(gsrc + off + lane * 16, &wbuf[0][off]);
        }
    }

    // build B fragments (x~), overlapping the stage
    half8 bf[2][5];
    #pragma unroll
    for (int pt = 0; pt < 2; ++pt) {
        const float* xr = X + (size_t)(wavebase + pt * 32 + col) * DDIM;
        #pragma unroll
        for (int s = 0; s < 4; ++s) {
            int c = s * 2 + h;
            float4 lo = *(const float4*)(xr + c * 8);
            float4 hi = *(const float4*)(xr + c * 8 + 4);
            half8 v;
            v[0] = (_Float16)lo.x; v[1] = (_Float16)lo.y;
            v[2] = (_Float16)lo.z; v[3] = (_Float16)lo.w;
            v[4] = (_Float16)hi.x; v[5] = (_Float16)hi.y;
            v[6] = (_Float16)hi.z; v[7] = (_Float16)hi.w;
            bf[pt][s] = v;
        }
        half8 v;
        #pragma unroll
        for (int e = 0; e < 8; ++e) v[e] = (_Float16)0.f;
        if (h == 0) { v[0] = (_Float16)1.f; v[1] = (_Float16)1.f; }
        bf[pt][4] = v;   // augmented slice: pairs with (-b_hi, -b_lo)
    }

    float mx0 = -INFINITY, sm0 = 0.f;
    float mx1 = -INFINITY, sm1 = 0.f;

    __syncthreads();   // emits vmcnt(0) drain: stage 0 complete

    const int g0 = col >> 2;   // swizzle key, same for both row-tiles
    int cur = 0;

    for (int k = 0; k < KCOMP; ++k) {
        // prefetch next component into the other buffer
        if (k + 1 < KCOMP) {
            const char* gsrc = (const char*)wt + (size_t)(k + 1) * WBYTES;
            #pragma unroll
            for (int j = 0; j < 8; ++j) {
                int off = wave * 8192 + j * 1024;
                gload_lds16(gsrc + off + lane * 16, &wbuf[cur ^ 1][off]);
            }
        }

        floatx16 a00 = {0.f}, a01 = {0.f}, a10 = {0.f}, a11 = {0.f};
        const char* wb = wbuf[cur];

        #pragma unroll
        for (int s = 0; s < 5; ++s) {
            int c = 2 * s + h;
            int p = c ^ g0;
            half8 A0 = *(const half8*)(wb + (size_t)col * 256 + p * 16);
            half8 A1 = *(const half8*)(wb + (size_t)(col + 32) * 256 + p * 16);
            a00 = __builtin_amdgcn_mfma_f32_32x32x16_f16(A0, bf[0][s], a00, 0, 0, 0);
            a01 = __builtin_amdgcn_mfma_f32_32x32x16_f16(A0, bf[1][s], a01, 0, 0, 0);
            a10 = __builtin_amdgcn_mfma_f32_32x32x16_f16(A1, bf[0][s], a10, 0, 0, 0);
            a11 = __builtin_amdgcn_mfma_f32_32x32x16_f16(A1, bf[1][s], a11, 0, 0, 0);
        }

        // maha = sum_i z_i^2 : per-lane partial over its 32 rows, + pair swap
        float s0 = 0.f, s1 = 0.f;
        #pragma unroll
        for (int r = 0; r < 16; ++r) {
            s0 += a00[r] * a00[r] + a10[r] * a10[r];
            s1 += a01[r] * a01[r] + a11[r] * a11[r];
        }
        s0 += __shfl_xor(s0, 32);
        s1 += __shfl_xor(s1, 32);

        float ck  = cst[k];
        float lp0 = ck - 0.5f * s0;
        float lp1 = ck - 0.5f * s1;
        float nm0 = fmaxf(mx0, lp0);
        sm0 = sm0 * __expf(mx0 - nm0) + __expf(lp0 - nm0); mx0 = nm0;
        float nm1 = fmaxf(mx1, lp1);
        sm1 = sm1 * __expf(mx1 - nm1) + __expf(lp1 - nm1); mx1 = nm1;

        __syncthreads();   // drains vmcnt (prefetch done) + protects buffers
        cur ^= 1;
    }

    if (h == 0) {
        out[wavebase + col]      = mx0 + logf(sm0);
        out[wavebase + 32 + col] = mx1 + logf(sm1);
    }
}

// ---------------------------------------------------------------------------
extern "C" void kernel_launch(void* const* d_in, const int* in_sizes, int n_in,
                              void* d_out, int out_size, void* d_ws, size_t ws_size,
                              hipStream_t stream) {
    const float* X   = (const float*)d_in[0];
    const float* loc = (const float*)d_in[1];
    const float* cov = (const float*)d_in[2];
    const float* pi  = (const float*)d_in[3];
    float* out = (float*)d_out;

    char* ws = (char*)d_ws;
    _Float16* wt = (_Float16*)ws;                                   // 512 KB
    float* cstp  = (float*)(ws + (size_t)KCOMP * DDIM * WROW * 2);  // 128 B

    const int n = in_sizes[0] / DDIM;   // 65536

    gmm_prep<<<KCOMP, 64, 0, stream>>>(loc, cov, pi, wt, cstp);
    gmm_main<<<n / 128, 128, 0, stream>>>(X, wt, cstp, out);
}

// Round 4
// 74.567 us; speedup vs baseline: 7.4443x; 1.7637x over previous
//
#include <hip/hip_runtime.h>
#include <math.h>

#define KCOMP 32
#define DDIM 64
#define LOG_2PI 1.8378770664093453f

#define WROW 128                      // f16 per swizzled W row (16 chunks x 8)
#define WBYTES (DDIM * WROW * 2)      // 16384 B per component

typedef _Float16 half8 __attribute__((ext_vector_type(8)));
typedef float floatx16 __attribute__((ext_vector_type(16)));

__device__ inline void gload_lds16(const void* g, void* l) {
    __builtin_amdgcn_global_load_lds(
        (const __attribute__((address_space(1))) void*)g,
        (__attribute__((address_space(3))) void*)l, 16, 0, 0);
}

__device__ inline float rdlane(float v, int l) {
    return __uint_as_float(__builtin_amdgcn_readlane(__float_as_uint(v), l));
}

// ---------------------------------------------------------------------------
// Prep: register-resident Cholesky + triangular inverse, one wave/component.
// Row t of Sigma/L lives in lane t's VGPRs; broadcasts via v_readlane (no LDS
// on the critical path). M is built column-per-lane, flushed to LDS once for
// the b / f16-emit phase. grid = KCOMP blocks x 64 threads.
// ---------------------------------------------------------------------------
__global__ __launch_bounds__(64, 1) void gmm_prep(const float* __restrict__ loc,
                                                  const float* __restrict__ cov,
                                                  const float* __restrict__ pi,
                                                  _Float16* __restrict__ wt,
                                                  float* __restrict__ cstout)
{
    const int k = blockIdx.x;
    const int t = threadIdx.x;

    __shared__ float M[DDIM][DDIM + 1];
    __shared__ float mu_s[DDIM];

    float Srow[DDIM];   // Sigma row t
    float Lrow[DDIM];   // L row t
    float Mcol[DDIM];   // M column t

    {
        const float4* Sg = (const float4*)(cov + (size_t)k * DDIM * DDIM + (size_t)t * DDIM);
        #pragma unroll
        for (int q = 0; q < DDIM / 4; ++q) {
            float4 v = Sg[q];
            Srow[q * 4 + 0] = v.x; Srow[q * 4 + 1] = v.y;
            Srow[q * 4 + 2] = v.z; Srow[q * 4 + 3] = v.w;
        }
    }
    mu_s[t] = loc[k * DDIM + t];

    // ---- left-looking Cholesky, rows in registers ----
    float hld = 0.f;   // uniform: 0.5 * sum log d_j
    #pragma unroll
    for (int j = 0; j < DDIM; ++j) {
        float a0 = 0.f, a1 = 0.f, a2 = 0.f, a3 = 0.f;
        #pragma unroll
        for (int c = 0; c < j; ++c) {
            float ljc = rdlane(Lrow[c], j);      // L[j][c], SGPR broadcast
            switch (c & 3) {
                case 0: a0 += Lrow[c] * ljc; break;
                case 1: a1 += Lrow[c] * ljc; break;
                case 2: a2 += Lrow[c] * ljc; break;
                default: a3 += Lrow[c] * ljc; break;
            }
        }
        float v = Srow[j] - ((a0 + a1) + (a2 + a3));
        float dj = __shfl(v, j);                 // diagonal d_j (pre-sqrt)
        float r = rsqrtf(dj);
        r = r * (1.5f - 0.5f * dj * r * r);      // one Newton step
        Lrow[j] = (t >= j) ? v * r : 0.f;
        hld += 0.5f * logf(dj);
    }

    // ---- M = L^{-1}: lane t builds column t, row-sequential ----
    #pragma unroll
    for (int i = 0; i < DDIM; ++i) {
        float a0 = 0.f, a1 = 0.f, a2 = 0.f, a3 = 0.f;
        #pragma unroll
        for (int c = 0; c < i; ++c) {
            float lic = rdlane(Lrow[c], i);      // L[i][c]
            switch (c & 3) {
                case 0: a0 += lic * Mcol[c]; break;
                case 1: a1 += lic * Mcol[c]; break;
                case 2: a2 += lic * Mcol[c]; break;
                default: a3 += lic * Mcol[c]; break;
            }
        }
        float dinv = 1.0f / rdlane(Lrow[i], i);  // uniform
        float s = (a0 + a1) + (a2 + a3);
        Mcol[i] = (t < i) ? (-s * dinv) : ((t == i) ? dinv : 0.f);
    }

    // flush M columns -> LDS rows (one time)
    #pragma unroll
    for (int i = 0; i < DDIM; ++i) M[i][t] = Mcol[i];
    __syncthreads();

    // ---- b_t = sum_j M[t][j] * mu[j] (upper of M is zero) ----
    float bt = 0.f;
    #pragma unroll 4
    for (int j = 0; j < DDIM; ++j) bt += M[t][j] * mu_s[j];

    // ---- emit swizzled f16 row t of W~ ----
    _Float16* wrow = wt + (size_t)k * DDIM * WROW + (size_t)t * WROW;
    const int g = (t >> 2) & 7;

    #pragma unroll
    for (int c = 0; c < 8; ++c) {          // data chunks: M row
        half8 v;
        #pragma unroll
        for (int e = 0; e < 8; ++e) v[e] = (_Float16)M[t][c * 8 + e];
        *(half8*)(wrow + (size_t)(c ^ g) * 8) = v;
    }
    {   // chunk 8: -b split hi/lo (pairs with x~=1,1)
        float nb = -bt;
        _Float16 h0 = (_Float16)nb;
        _Float16 h1 = (_Float16)(nb - (float)h0);
        half8 v;
        #pragma unroll
        for (int e = 0; e < 8; ++e) v[e] = (_Float16)0.f;
        v[0] = h0; v[1] = h1;
        *(half8*)(wrow + (size_t)(8 ^ g) * 8) = v;
    }
    #pragma unroll
    for (int c = 9; c < 16; ++c) {         // zero padding chunks
        half8 v;
        #pragma unroll
        for (int e = 0; e < 8; ++e) v[e] = (_Float16)0.f;
        *(half8*)(wrow + (size_t)(c ^ g) * 8) = v;
    }

    if (t == 0) {
        float mxp = pi[0];
        for (int i = 1; i < KCOMP; ++i) mxp = fmaxf(mxp, pi[i]);
        float s = 0.f;
        for (int i = 0; i < KCOMP; ++i) s += __expf(pi[i] - mxp);
        float lse = mxp + logf(s);
        cstout[k] = (pi[k] - lse) - hld - 0.5f * (float)DDIM * LOG_2PI;
    }
}

// ---------------------------------------------------------------------------
// Main: MFMA z = W~ x~ per component; C rows = out-dim i, cols = points.
// 128 threads (2 waves), 64 points per wave. W~ double-buffered in LDS via
// global_load_lds; x~ B-fragments resident in registers for all 32 comps.
// ---------------------------------------------------------------------------
__global__ __launch_bounds__(128) void gmm_main(const float* __restrict__ X,
                                                const _Float16* __restrict__ wt,
                                                const float* __restrict__ cst,
                                                float* __restrict__ out)
{
    __shared__ char wbuf[2][WBYTES];      // 32 KB

    const int tid  = threadIdx.x;
    const int wave = tid >> 6;
    const int lane = tid & 63;
    const int col  = lane & 31;
    const int h    = lane >> 5;
    const int wavebase = blockIdx.x * 128 + wave * 64;

    // issue stage of component 0 into buf 0 (8 KB per wave)
    {
        const char* gsrc = (const char*)wt;
        #pragma unroll
        for (int j = 0; j < 8; ++j) {
            int off = wave * 8192 + j * 1024;
            gload_lds16(gsrc + off + lane * 16, &wbuf[0][off]);
        }
    }

    // build B fragments (x~), overlapping the stage
    half8 bf[2][5];
    #pragma unroll
    for (int pt = 0; pt < 2; ++pt) {
        const float* xr = X + (size_t)(wavebase + pt * 32 + col) * DDIM;
        #pragma unroll
        for (int s = 0; s < 4; ++s) {
            int c = s * 2 + h;
            float4 lo = *(const float4*)(xr + c * 8);
            float4 hi = *(const float4*)(xr + c * 8 + 4);
            half8 v;
            v[0] = (_Float16)lo.x; v[1] = (_Float16)lo.y;
            v[2] = (_Float16)lo.z; v[3] = (_Float16)lo.w;
            v[4] = (_Float16)hi.x; v[5] = (_Float16)hi.y;
            v[6] = (_Float16)hi.z; v[7] = (_Float16)hi.w;
            bf[pt][s] = v;
        }
        half8 v;
        #pragma unroll
        for (int e = 0; e < 8; ++e) v[e] = (_Float16)0.f;
        if (h == 0) { v[0] = (_Float16)1.f; v[1] = (_Float16)1.f; }
        bf[pt][4] = v;   // augmented slice: pairs with (-b_hi, -b_lo)
    }

    float mx0 = -INFINITY, sm0 = 0.f;
    float mx1 = -INFINITY, sm1 = 0.f;

    __syncthreads();   // emits vmcnt(0) drain: stage 0 complete

    const int g0 = col >> 2;   // swizzle key, same for both row-tiles
    int cur = 0;

    for (int k = 0; k < KCOMP; ++k) {
        // prefetch next component into the other buffer
        if (k + 1 < KCOMP) {
            const char* gsrc = (const char*)wt + (size_t)(k + 1) * WBYTES;
            #pragma unroll
            for (int j = 0; j < 8; ++j) {
                int off = wave * 8192 + j * 1024;
                gload_lds16(gsrc + off + lane * 16, &wbuf[cur ^ 1][off]);
            }
        }

        floatx16 a00 = {0.f}, a01 = {0.f}, a10 = {0.f}, a11 = {0.f};
        const char* wb = wbuf[cur];

        #pragma unroll
        for (int s = 0; s < 5; ++s) {
            int c = 2 * s + h;
            int p = c ^ g0;
            half8 A0 = *(const half8*)(wb + (size_t)col * 256 + p * 16);
            half8 A1 = *(const half8*)(wb + (size_t)(col + 32) * 256 + p * 16);
            a00 = __builtin_amdgcn_mfma_f32_32x32x16_f16(A0, bf[0][s], a00, 0, 0, 0);
            a01 = __builtin_amdgcn_mfma_f32_32x32x16_f16(A0, bf[1][s], a01, 0, 0, 0);
            a10 = __builtin_amdgcn_mfma_f32_32x32x16_f16(A1, bf[0][s], a10, 0, 0, 0);
            a11 = __builtin_amdgcn_mfma_f32_32x32x16_f16(A1, bf[1][s], a11, 0, 0, 0);
        }

        // maha = sum_i z_i^2 : per-lane partial over its 32 rows, + pair swap
        float s0 = 0.f, s1 = 0.f;
        #pragma unroll
        for (int r = 0; r < 16; ++r) {
            s0 += a00[r] * a00[r] + a10[r] * a10[r];
            s1 += a01[r] * a01[r] + a11[r] * a11[r];
        }
        s0 += __shfl_xor(s0, 32);
        s1 += __shfl_xor(s1, 32);

        float ck  = cst[k];
        float lp0 = ck - 0.5f * s0;
        float lp1 = ck - 0.5f * s1;
        float nm0 = fmaxf(mx0, lp0);
        sm0 = sm0 * __expf(mx0 - nm0) + __expf(lp0 - nm0); mx0 = nm0;
        float nm1 = fmaxf(mx1, lp1);
        sm1 = sm1 * __expf(mx1 - nm1) + __expf(lp1 - nm1); mx1 = nm1;

        __syncthreads();   // drains vmcnt (prefetch done) + protects buffers
        cur ^= 1;
    }

    if (h == 0) {
        out[wavebase + col]      = mx0 + logf(sm0);
        out[wavebase + 32 + col] = mx1 + logf(sm1);
    }
}

// ---------------------------------------------------------------------------
extern "C" void kernel_launch(void* const* d_in, const int* in_sizes, int n_in,
                              void* d_out, int out_size, void* d_ws, size_t ws_size,
                              hipStream_t stream) {
    const float* X   = (const float*)d_in[0];
    const float* loc = (const float*)d_in[1];
    const float* cov = (const float*)d_in[2];
    const float* pi  = (const float*)d_in[3];
    float* out = (float*)d_out;

    char* ws = (char*)d_ws;
    _Float16* wt = (_Float16*)ws;                                   // 512 KB
    float* cstp  = (float*)(ws + (size_t)KCOMP * DDIM * WROW * 2);  // 128 B

    const int n = in_sizes[0] / DDIM;   // 65536

    gmm_prep<<<KCOMP, 64, 0, stream>>>(loc, cov, pi, wt, cstp);
    gmm_main<<<n / 128, 128, 0, stream>>>(X, wt, cstp, out);
}

// Round 5
// 62.709 us; speedup vs baseline: 8.8520x; 1.1891x over previous
//
#include <hip/hip_runtime.h>
#include <math.h>

#define KCOMP 32
#define DDIM 64
#define LOG_2PI 1.8378770664093453f

#define WROW 128                      // f16 per swizzled W row (16 chunks x 8)
#define WBYTES (DDIM * WROW * 2)      // 16384 B per component

typedef _Float16 half8 __attribute__((ext_vector_type(8)));
typedef float floatx16 __attribute__((ext_vector_type(16)));

__device__ inline void gload_lds16(const void* g, void* l) {
    __builtin_amdgcn_global_load_lds(
        (const __attribute__((address_space(1))) void*)g,
        (__attribute__((address_space(3))) void*)l, 16, 0, 0);
}

__device__ inline float rdlane(float v, int l) {
    return __uint_as_float(__builtin_amdgcn_readlane(__float_as_uint(v), l));
}

// ---------------------------------------------------------------------------
// Prep: register-resident Cholesky + triangular inverse, one wave/component.
// Row t of Sigma/L lives in lane t's VGPRs; broadcasts via v_readlane (no LDS
// on the critical path). M is built column-per-lane, flushed to LDS once for
// the b / f16-emit phase. grid = KCOMP blocks x 64 threads.
// ---------------------------------------------------------------------------
__global__ __launch_bounds__(64, 1) void gmm_prep(const float* __restrict__ loc,
                                                  const float* __restrict__ cov,
                                                  const float* __restrict__ pi,
                                                  _Float16* __restrict__ wt,
                                                  float* __restrict__ cstout)
{
    const int k = blockIdx.x;
    const int t = threadIdx.x;

    __shared__ float M[DDIM][DDIM + 1];
    __shared__ float mu_s[DDIM];

    float Srow[DDIM];   // Sigma row t
    float Lrow[DDIM];   // L row t
    float Mcol[DDIM];   // M column t

    {
        const float4* Sg = (const float4*)(cov + (size_t)k * DDIM * DDIM + (size_t)t * DDIM);
        #pragma unroll
        for (int q = 0; q < DDIM / 4; ++q) {
            float4 v = Sg[q];
            Srow[q * 4 + 0] = v.x; Srow[q * 4 + 1] = v.y;
            Srow[q * 4 + 2] = v.z; Srow[q * 4 + 3] = v.w;
        }
    }
    mu_s[t] = loc[k * DDIM + t];

    // ---- left-looking Cholesky, rows in registers ----
    float hld = 0.f;   // uniform: 0.5 * sum log d_j
    #pragma unroll
    for (int j = 0; j < DDIM; ++j) {
        float a0 = 0.f, a1 = 0.f, a2 = 0.f, a3 = 0.f;
        #pragma unroll
        for (int c = 0; c < j; ++c) {
            float ljc = rdlane(Lrow[c], j);      // L[j][c], SGPR broadcast
            switch (c & 3) {
                case 0: a0 += Lrow[c] * ljc; break;
                case 1: a1 += Lrow[c] * ljc; break;
                case 2: a2 += Lrow[c] * ljc; break;
                default: a3 += Lrow[c] * ljc; break;
            }
        }
        float v = Srow[j] - ((a0 + a1) + (a2 + a3));
        float dj = __shfl(v, j);                 // diagonal d_j (pre-sqrt)
        float r = rsqrtf(dj);
        r = r * (1.5f - 0.5f * dj * r * r);      // one Newton step
        Lrow[j] = (t >= j) ? v * r : 0.f;
        hld += 0.5f * logf(dj);
    }

    // ---- M = L^{-1}: lane t builds column t, row-sequential ----
    #pragma unroll
    for (int i = 0; i < DDIM; ++i) {
        float a0 = 0.f, a1 = 0.f, a2 = 0.f, a3 = 0.f;
        #pragma unroll
        for (int c = 0; c < i; ++c) {
            float lic = rdlane(Lrow[c], i);      // L[i][c]
            switch (c & 3) {
                case 0: a0 += lic * Mcol[c]; break;
                case 1: a1 += lic * Mcol[c]; break;
                case 2: a2 += lic * Mcol[c]; break;
                default: a3 += lic * Mcol[c]; break;
            }
        }
        float dinv = 1.0f / rdlane(Lrow[i], i);  // uniform
        float s = (a0 + a1) + (a2 + a3);
        Mcol[i] = (t < i) ? (-s * dinv) : ((t == i) ? dinv : 0.f);
    }

    // flush M columns -> LDS rows (one time)
    #pragma unroll
    for (int i = 0; i < DDIM; ++i) M[i][t] = Mcol[i];
    __syncthreads();

    // ---- b_t = sum_j M[t][j] * mu[j] (upper of M is zero) ----
    float bt = 0.f;
    #pragma unroll 4
    for (int j = 0; j < DDIM; ++j) bt += M[t][j] * mu_s[j];

    // ---- emit swizzled f16 row t of W~ ----
    // swizzle key g = row & 7: within a 16-lane ds_read_b128 group (16
    // consecutive rows, same chunk c) the chunk positions c^g cover all 8
    // bank groups exactly twice -> 2-way (free). (row>>2 variant was 4-way.)
    _Float16* wrow = wt + (size_t)k * DDIM * WROW + (size_t)t * WROW;
    const int g = t & 7;

    #pragma unroll
    for (int c = 0; c < 8; ++c) {          // data chunks: M row
        half8 v;
        #pragma unroll
        for (int e = 0; e < 8; ++e) v[e] = (_Float16)M[t][c * 8 + e];
        *(half8*)(wrow + (size_t)(c ^ g) * 8) = v;
    }
    {   // chunk 8: -b split hi/lo (pairs with x~=1,1)
        float nb = -bt;
        _Float16 h0 = (_Float16)nb;
        _Float16 h1 = (_Float16)(nb - (float)h0);
        half8 v;
        #pragma unroll
        for (int e = 0; e < 8; ++e) v[e] = (_Float16)0.f;
        v[0] = h0; v[1] = h1;
        *(half8*)(wrow + (size_t)(8 ^ g) * 8) = v;
    }
    #pragma unroll
    for (int c = 9; c < 16; ++c) {         // zero padding chunks
        half8 v;
        #pragma unroll
        for (int e = 0; e < 8; ++e) v[e] = (_Float16)0.f;
        *(half8*)(wrow + (size_t)(c ^ g) * 8) = v;
    }

    if (t == 0) {
        float mxp = pi[0];
        for (int i = 1; i < KCOMP; ++i) mxp = fmaxf(mxp, pi[i]);
        float s = 0.f;
        for (int i = 0; i < KCOMP; ++i) s += __expf(pi[i] - mxp);
        float lse = mxp + logf(s);
        cstout[k] = (pi[k] - lse) - hld - 0.5f * (float)DDIM * LOG_2PI;
    }
}

// ---------------------------------------------------------------------------
// Main: MFMA z = W~ x~ per component. 256 threads = 4 waves x 32 points each
// (2048 waves total = 2 waves/SIMD for cross-wave MFMA/VALU/LDS overlap).
// W~ double-buffered in LDS via global_load_lds; per-block component-order
// rotation spreads L2 traffic and de-phases the barrier drains.
// ---------------------------------------------------------------------------
__global__ __launch_bounds__(256) void gmm_main(const float* __restrict__ X,
                                                const _Float16* __restrict__ wt,
                                                const float* __restrict__ cst,
                                                float* __restrict__ out)
{
    __shared__ char wbuf[2][WBYTES];      // 32 KB

    const int tid  = threadIdx.x;
    const int wave = tid >> 6;
    const int lane = tid & 63;
    const int col  = lane & 31;
    const int h    = lane >> 5;
    const int bid  = blockIdx.x;
    const int point = bid * 128 + wave * 32 + col;

    // issue stage of first component (rotated) into buf 0 (4 KB per wave)
    {
        const char* gsrc = (const char*)wt + (size_t)(bid & 31) * WBYTES;
        #pragma unroll
        for (int j = 0; j < 4; ++j) {
            int off = wave * 4096 + j * 1024;
            gload_lds16(gsrc + off + lane * 16, &wbuf[0][off]);
        }
    }

    // build B fragments (x~), overlapping the stage
    half8 bf[5];
    {
        const float* xr = X + (size_t)point * DDIM;
        #pragma unroll
        for (int s = 0; s < 4; ++s) {
            int c = s * 2 + h;
            float4 lo = *(const float4*)(xr + c * 8);
            float4 hi = *(const float4*)(xr + c * 8 + 4);
            half8 v;
            v[0] = (_Float16)lo.x; v[1] = (_Float16)lo.y;
            v[2] = (_Float16)lo.z; v[3] = (_Float16)lo.w;
            v[4] = (_Float16)hi.x; v[5] = (_Float16)hi.y;
            v[6] = (_Float16)hi.z; v[7] = (_Float16)hi.w;
            bf[s] = v;
        }
        half8 v;
        #pragma unroll
        for (int e = 0; e < 8; ++e) v[e] = (_Float16)0.f;
        if (h == 0) { v[0] = (_Float16)1.f; v[1] = (_Float16)1.f; }
        bf[4] = v;   // augmented slice: pairs with (-b_hi, -b_lo)
    }

    float mx = -INFINITY, sm = 0.f;

    __syncthreads();   // emits vmcnt(0) drain: stage 0 complete

    const int g0 = col & 7;   // swizzle key (rows col and col+32 share it)
    int cur = 0;

    for (int k = 0; k < KCOMP; ++k) {
        const int comp = (k + bid) & 31;
        // prefetch next component into the other buffer
        if (k + 1 < KCOMP) {
            const int cnext = (k + 1 + bid) & 31;
            const char* gsrc = (const char*)wt + (size_t)cnext * WBYTES;
            #pragma unroll
            for (int j = 0; j < 4; ++j) {
                int off = wave * 4096 + j * 1024;
                gload_lds16(gsrc + off + lane * 16, &wbuf[cur ^ 1][off]);
            }
        }

        floatx16 a0 = {0.f}, a1 = {0.f};
        const char* wb = wbuf[cur];

        #pragma unroll
        for (int s = 0; s < 5; ++s) {
            int c = 2 * s + h;
            int p = c ^ g0;
            half8 A0 = *(const half8*)(wb + (size_t)col * 256 + p * 16);
            half8 A1 = *(const half8*)(wb + (size_t)(col + 32) * 256 + p * 16);
            a0 = __builtin_amdgcn_mfma_f32_32x32x16_f16(A0, bf[s], a0, 0, 0, 0);
            a1 = __builtin_amdgcn_mfma_f32_32x32x16_f16(A1, bf[s], a1, 0, 0, 0);
        }

        // maha = sum_i z_i^2 : per-lane partial over rows, + half-pair swap
        float s0 = 0.f;
        #pragma unroll
        for (int r = 0; r < 16; ++r) {
            s0 += a0[r] * a0[r] + a1[r] * a1[r];
        }
        s0 += __shfl_xor(s0, 32);

        float lp = cst[comp] - 0.5f * s0;
        float nm = fmaxf(mx, lp);
        sm = sm * __expf(mx - nm) + __expf(lp - nm); mx = nm;

        __syncthreads();   // drains vmcnt (prefetch done) + protects buffers
        cur ^= 1;
    }

    if (h == 0) {
        out[point] = mx + logf(sm);
    }
}

// ---------------------------------------------------------------------------
extern "C" void kernel_launch(void* const* d_in, const int* in_sizes, int n_in,
                              void* d_out, int out_size, void* d_ws, size_t ws_size,
                              hipStream_t stream) {
    const float* X   = (const float*)d_in[0];
    const float* loc = (const float*)d_in[1];
    const float* cov = (const float*)d_in[2];
    const float* pi  = (const float*)d_in[3];
    float* out = (float*)d_out;

    char* ws = (char*)d_ws;
    _Float16* wt = (_Float16*)ws;                                   // 512 KB
    float* cstp  = (float*)(ws + (size_t)KCOMP * DDIM * WROW * 2);  // 128 B

    const int n = in_sizes[0] / DDIM;   // 65536

    gmm_prep<<<KCOMP, 64, 0, stream>>>(loc, cov, pi, wt, cstp);
    gmm_main<<<n / 128, 256, 0, stream>>>(X, wt, cstp, out);
}

// Round 6
// 61.947 us; speedup vs baseline: 8.9610x; 1.0123x over previous
//
#include <hip/hip_runtime.h>
#include <math.h>

#define KCOMP 32
#define DDIM 64
#define LOG_2PI 1.8378770664093453f

#define WROW 128                      // f16 per swizzled W row (16 chunks x 8)
#define WBYTES (DDIM * WROW * 2)      // 16384 B per component

typedef _Float16 half8 __attribute__((ext_vector_type(8)));
typedef float floatx16 __attribute__((ext_vector_type(16)));

__device__ inline void gload_lds16(const void* g, void* l) {
    __builtin_amdgcn_global_load_lds(
        (const __attribute__((address_space(1))) void*)g,
        (__attribute__((address_space(3))) void*)l, 16, 0, 0);
}

__device__ inline float rdlane(float v, int l) {
    return __uint_as_float(__builtin_amdgcn_readlane(__float_as_uint(v), l));
}

// ---------------------------------------------------------------------------
// Prep: register-resident Cholesky + triangular inverse, one wave/component.
// Row t of Sigma/L lives in lane t's VGPRs; ALL broadcasts via v_readlane
// (constant lane index -> SGPR, no LDS/ds_bpermute on the critical path).
// grid = KCOMP blocks x 64 threads.
// ---------------------------------------------------------------------------
__global__ __launch_bounds__(64, 1) void gmm_prep(const float* __restrict__ loc,
                                                  const float* __restrict__ cov,
                                                  const float* __restrict__ pi,
                                                  _Float16* __restrict__ wt,
                                                  float* __restrict__ cstout)
{
    const int k = blockIdx.x;
    const int t = threadIdx.x;

    __shared__ float M[DDIM][DDIM + 1];
    __shared__ float mu_s[DDIM];

    float Srow[DDIM];   // Sigma row t
    float Lrow[DDIM];   // L row t
    float Mcol[DDIM];   // M column t

    {
        const float4* Sg = (const float4*)(cov + (size_t)k * DDIM * DDIM + (size_t)t * DDIM);
        #pragma unroll
        for (int q = 0; q < DDIM / 4; ++q) {
            float4 v = Sg[q];
            Srow[q * 4 + 0] = v.x; Srow[q * 4 + 1] = v.y;
            Srow[q * 4 + 2] = v.z; Srow[q * 4 + 3] = v.w;
        }
    }
    mu_s[t] = loc[k * DDIM + t];

    // ---- left-looking Cholesky, rows in registers ----
    float hld = 0.f;   // uniform: 0.5 * sum log d_j
    #pragma unroll
    for (int j = 0; j < DDIM; ++j) {
        float a0 = 0.f, a1 = 0.f, a2 = 0.f, a3 = 0.f;
        #pragma unroll
        for (int c = 0; c < j; ++c) {
            float ljc = rdlane(Lrow[c], j);      // L[j][c], SGPR broadcast
            switch (c & 3) {
                case 0: a0 += Lrow[c] * ljc; break;
                case 1: a1 += Lrow[c] * ljc; break;
                case 2: a2 += Lrow[c] * ljc; break;
                default: a3 += Lrow[c] * ljc; break;
            }
        }
        float v = Srow[j] - ((a0 + a1) + (a2 + a3));
        float dj = rdlane(v, j);                 // diagonal d_j (pre-sqrt), readlane not shfl
        float r = rsqrtf(dj);
        r = r * (1.5f - 0.5f * dj * r * r);      // one Newton step
        Lrow[j] = (t >= j) ? v * r : 0.f;
        hld += 0.5f * logf(dj);
    }

    // ---- M = L^{-1}: lane t builds column t, row-sequential ----
    #pragma unroll
    for (int i = 0; i < DDIM; ++i) {
        float a0 = 0.f, a1 = 0.f, a2 = 0.f, a3 = 0.f;
        #pragma unroll
        for (int c = 0; c < i; ++c) {
            float lic = rdlane(Lrow[c], i);      // L[i][c]
            switch (c & 3) {
                case 0: a0 += lic * Mcol[c]; break;
                case 1: a1 += lic * Mcol[c]; break;
                case 2: a2 += lic * Mcol[c]; break;
                default: a3 += lic * Mcol[c]; break;
            }
        }
        float dinv = 1.0f / rdlane(Lrow[i], i);  // uniform
        float s = (a0 + a1) + (a2 + a3);
        Mcol[i] = (t < i) ? (-s * dinv) : ((t == i) ? dinv : 0.f);
    }

    // flush M columns -> LDS rows (one time)
    #pragma unroll
    for (int i = 0; i < DDIM; ++i) M[i][t] = Mcol[i];
    __syncthreads();

    // ---- b_t = sum_j M[t][j] * mu[j] (upper of M is zero) ----
    float bt = 0.f;
    #pragma unroll 4
    for (int j = 0; j < DDIM; ++j) bt += M[t][j] * mu_s[j];

    // ---- emit swizzled f16 row t of W~ ----
    // swizzle key g = row & 7: within a 16-lane ds_read_b128 group (16
    // consecutive rows, same chunk c) the chunk positions c^g cover all 8
    // bank groups exactly twice -> 2-way (free).
    _Float16* wrow = wt + (size_t)k * DDIM * WROW + (size_t)t * WROW;
    const int g = t & 7;

    #pragma unroll
    for (int c = 0; c < 8; ++c) {          // data chunks: M row
        half8 v;
        #pragma unroll
        for (int e = 0; e < 8; ++e) v[e] = (_Float16)M[t][c * 8 + e];
        *(half8*)(wrow + (size_t)(c ^ g) * 8) = v;
    }
    {   // chunk 8: -b split hi/lo (pairs with x~=1,1)
        float nb = -bt;
        _Float16 h0 = (_Float16)nb;
        _Float16 h1 = (_Float16)(nb - (float)h0);
        half8 v;
        #pragma unroll
        for (int e = 0; e < 8; ++e) v[e] = (_Float16)0.f;
        v[0] = h0; v[1] = h1;
        *(half8*)(wrow + (size_t)(8 ^ g) * 8) = v;
    }
    #pragma unroll
    for (int c = 9; c < 16; ++c) {         // zero padding chunks
        half8 v;
        #pragma unroll
        for (int e = 0; e < 8; ++e) v[e] = (_Float16)0.f;
        *(half8*)(wrow + (size_t)(c ^ g) * 8) = v;
    }

    if (t == 0) {
        float mxp = pi[0];
        for (int i = 1; i < KCOMP; ++i) mxp = fmaxf(mxp, pi[i]);
        float s = 0.f;
        for (int i = 0; i < KCOMP; ++i) s += __expf(pi[i] - mxp);
        float lse = mxp + logf(s);
        cstout[k] = (pi[k] - lse) - hld - 0.5f * (float)DDIM * LOG_2PI;
    }
}

// ---------------------------------------------------------------------------
// Main: MFMA z = W~ x~. 256 threads = 4 waves x 32 points (2048 waves total =
// 2 waves/SIMD). TWO components staged per iteration (2 x 32 KB LDS buffers,
// still 2 blocks/CU) -> 16 barrier intervals instead of 32, 2 independent
// accumulator pairs per interval for ILP. Per-block component rotation
// spreads L2 traffic and de-phases the drains.
// ---------------------------------------------------------------------------
__global__ __launch_bounds__(256) void gmm_main(const float* __restrict__ X,
                                                const _Float16* __restrict__ wt,
                                                const float* __restrict__ cst,
                                                float* __restrict__ out)
{
    __shared__ char wbuf[2][2 * WBYTES];      // 64 KB

    const int tid  = threadIdx.x;
    const int wave = tid >> 6;
    const int lane = tid & 63;
    const int col  = lane & 31;
    const int h    = lane >> 5;
    const int bid  = blockIdx.x;
    const int point = bid * 128 + wave * 32 + col;
    const int rot  = (bid * 2) & 31;          // even rotation keeps pairs intact

    // issue stage of first component pair into buf 0 (8 KB per wave)
    {
        const char* gsrc = (const char*)wt + (size_t)rot * WBYTES;
        #pragma unroll
        for (int j = 0; j < 8; ++j) {
            int off = wave * 8192 + j * 1024;
            gload_lds16(gsrc + off + lane * 16, &wbuf[0][off]);
        }
    }

    // build B fragments (x~), overlapping the stage
    half8 bf[5];
    {
        const float* xr = X + (size_t)point * DDIM;
        #pragma unroll
        for (int s = 0; s < 4; ++s) {
            int c = s * 2 + h;
            float4 lo = *(const float4*)(xr + c * 8);
            float4 hi = *(const float4*)(xr + c * 8 + 4);
            half8 v;
            v[0] = (_Float16)lo.x; v[1] = (_Float16)lo.y;
            v[2] = (_Float16)lo.z; v[3] = (_Float16)lo.w;
            v[4] = (_Float16)hi.x; v[5] = (_Float16)hi.y;
            v[6] = (_Float16)hi.z; v[7] = (_Float16)hi.w;
            bf[s] = v;
        }
        half8 v;
        #pragma unroll
        for (int e = 0; e < 8; ++e) v[e] = (_Float16)0.f;
        if (h == 0) { v[0] = (_Float16)1.f; v[1] = (_Float16)1.f; }
        bf[4] = v;   // augmented slice: pairs with (-b_hi, -b_lo)
    }

    float mx = -INFINITY, sm = 0.f;

    __syncthreads();   // emits vmcnt(0) drain: stage 0 complete

    const int g0 = col & 7;   // swizzle key (rows col and col+32 share it)
    int cur = 0;

    #pragma unroll 1
    for (int kk = 0; kk < KCOMP / 2; ++kk) {
        const int cb = (2 * kk + rot) & 31;        // even; pair = cb, cb+1
        // prefetch next pair into the other buffer (32 KB contiguous)
        if (kk + 1 < KCOMP / 2) {
            const int cbn = (2 * kk + 2 + rot) & 31;
            const char* gsrc = (const char*)wt + (size_t)cbn * WBYTES;
            #pragma unroll
            for (int j = 0; j < 8; ++j) {
                int off = wave * 8192 + j * 1024;
                gload_lds16(gsrc + off + lane * 16, &wbuf[cur ^ 1][off]);
            }
        }

        floatx16 p0 = {0.f}, p1 = {0.f};   // comp cb   : rows 0-31 / 32-63
        floatx16 q0 = {0.f}, q1 = {0.f};   // comp cb+1
        const char* wb0 = wbuf[cur];
        const char* wb1 = wbuf[cur] + WBYTES;

        #pragma unroll
        for (int s = 0; s < 5; ++s) {
            int c = 2 * s + h;
            int p = c ^ g0;
            half8 A0 = *(const half8*)(wb0 + (size_t)col * 256 + p * 16);
            half8 A1 = *(const half8*)(wb0 + (size_t)(col + 32) * 256 + p * 16);
            half8 B0 = *(const half8*)(wb1 + (size_t)col * 256 + p * 16);
            half8 B1 = *(const half8*)(wb1 + (size_t)(col + 32) * 256 + p * 16);
            p0 = __builtin_amdgcn_mfma_f32_32x32x16_f16(A0, bf[s], p0, 0, 0, 0);
            p1 = __builtin_amdgcn_mfma_f32_32x32x16_f16(A1, bf[s], p1, 0, 0, 0);
            q0 = __builtin_amdgcn_mfma_f32_32x32x16_f16(B0, bf[s], q0, 0, 0, 0);
            q1 = __builtin_amdgcn_mfma_f32_32x32x16_f16(B1, bf[s], q1, 0, 0, 0);
        }

        // maha = sum_i z_i^2 per comp: per-lane partial + half-pair swap
        float s0 = 0.f, s1 = 0.f;
        #pragma unroll
        for (int r = 0; r < 16; ++r) {
            s0 += p0[r] * p0[r] + p1[r] * p1[r];
            s1 += q0[r] * q0[r] + q1[r] * q1[r];
        }
        s0 += __shfl_xor(s0, 32);
        s1 += __shfl_xor(s1, 32);

        float lp0 = cst[cb]     - 0.5f * s0;
        float lp1 = cst[cb + 1] - 0.5f * s1;
        float nm = fmaxf(mx, fmaxf(lp0, lp1));
        sm = sm * __expf(mx - nm) + __expf(lp0 - nm) + __expf(lp1 - nm);
        mx = nm;

        __syncthreads();   // drains vmcnt (prefetch done) + protects buffers
        cur ^= 1;
    }

    if (h == 0) {
        out[point] = mx + logf(sm);
    }
}

// ---------------------------------------------------------------------------
extern "C" void kernel_launch(void* const* d_in, const int* in_sizes, int n_in,
                              void* d_out, int out_size, void* d_ws, size_t ws_size,
                              hipStream_t stream) {
    const float* X   = (const float*)d_in[0];
    const float* loc = (const float*)d_in[1];
    const float* cov = (const float*)d_in[2];
    const float* pi  = (const float*)d_in[3];
    float* out = (float*)d_out;

    char* ws = (char*)d_ws;
    _Float16* wt = (_Float16*)ws;                                   // 512 KB
    float* cstp  = (float*)(ws + (size_t)KCOMP * DDIM * WROW * 2);  // 128 B

    const int n = in_sizes[0] / DDIM;   // 65536

    gmm_prep<<<KCOMP, 64, 0, stream>>>(loc, cov, pi, wt, cstp);
    gmm_main<<<n / 128, 256, 0, stream>>>(X, wt, cstp, out);
}